// Round 1
// baseline (1286.779 us; speedup 1.0000x reference)
//
#include <hip/hip_runtime.h>
#include <hip/hip_bf16.h>
#include <cstdint>

#define N_NODES 100000
#define N_EDGES 1600000
#define N_GRAPHS 2000
#define IN_DIM 37
#define HID 128

// ---------------- CSR build ----------------

__global__ __launch_bounds__(256) void zero_kernel(int* __restrict__ p, int n) {
    int i = blockIdx.x * 256 + threadIdx.x;
    if (i < n) p[i] = 0;
}

__global__ __launch_bounds__(256) void hist_kernel(const int* __restrict__ ei, int* __restrict__ cnt) {
    int e = blockIdx.x * 256 + threadIdx.x;
    if (e < N_EDGES) {
        int d = ei[N_EDGES + e];  // dst
        atomicAdd(&cnt[d], 1);
    }
}

// exclusive scan of cnt -> rowptr (and cursor copy), also deg as float
__global__ __launch_bounds__(1024) void scan_kernel(int* __restrict__ cnt,
                                                    int* __restrict__ rowptr,
                                                    float* __restrict__ degf) {
    __shared__ int wsum[16];
    const int tid = threadIdx.x;
    const int lane = tid & 63;
    const int wv = tid >> 6;  // 0..15
    int running = 0;
    for (int base = 0; base < N_NODES; base += 1024) {
        int i = base + tid;
        int v0 = (i < N_NODES) ? cnt[i] : 0;
        // wave-inclusive scan
        int v = v0;
        #pragma unroll
        for (int off = 1; off < 64; off <<= 1) {
            int n = __shfl_up(v, off, 64);
            if (lane >= off) v += n;
        }
        if (lane == 63) wsum[wv] = v;
        __syncthreads();
        int woff = 0, tot = 0;
        #pragma unroll
        for (int w = 0; w < 16; w++) {
            int s = wsum[w];
            if (w < wv) woff += s;
            tot += s;
        }
        int excl = running + woff + v - v0;
        if (i < N_NODES) {
            rowptr[i] = excl;
            cnt[i] = excl;          // cursor for fill
            degf[i] = (float)v0;
        }
        running += tot;
        __syncthreads();
    }
    if (tid == 0) rowptr[N_NODES] = running;
}

__global__ __launch_bounds__(256) void fill_kernel(const int* __restrict__ ei,
                                                   int* __restrict__ cursor,
                                                   int* __restrict__ col) {
    int e = blockIdx.x * 256 + threadIdx.x;
    if (e < N_EDGES) {
        int s = ei[e];            // src
        int d = ei[N_EDGES + e];  // dst
        int pos = atomicAdd(&cursor[d], 1);
        col[pos] = s;
    }
}

// ---------------- per-layer fused GEMM ----------------
// B   = h @ W2
// OUT = deg * (h @ W1 + b1) + (h @ W3 + b3)
// (aggregation -agg subtracted later by gather kernel; ReLU deferred)

template <int DI, bool RELU_IN>
__global__ __launch_bounds__(256) void leconv_gemm(
    const float* __restrict__ h,
    const float* __restrict__ W1, const float* __restrict__ b1,
    const float* __restrict__ W2,
    const float* __restrict__ W3, const float* __restrict__ b3,
    const float* __restrict__ deg,
    float* __restrict__ Bout, float* __restrict__ OUT) {
    constexpr int TILE_R = 64;
    constexpr int DIP = DI + 4;  // pad to dodge bank conflicts
    __shared__ float hs[TILE_R][DIP];

    const int row0 = blockIdx.x * TILE_R;
    const int tid = threadIdx.x;

    for (int idx = tid; idx < TILE_R * DI; idx += 256) {
        int r = idx / DI;
        int k = idx - r * DI;
        int gr = row0 + r;
        float v = (gr < N_NODES) ? h[(size_t)gr * DI + k] : 0.f;
        if (RELU_IN) v = fmaxf(v, 0.f);
        hs[r][k] = v;
    }
    __syncthreads();

    const int tr = tid >> 4;  // 0..15 : rows tr, tr+16, tr+32, tr+48
    const int tc = tid & 15;  // cols tc*8 .. tc*8+7

    float acc[4][8];
    float aacc[4][8];

    auto mm = [&](const float* __restrict__ W) {
        #pragma unroll
        for (int i = 0; i < 4; i++)
            #pragma unroll
            for (int j = 0; j < 8; j++) acc[i][j] = 0.f;
        #pragma unroll 4
        for (int k = 0; k < DI; k++) {
            const float4 w0 = *(const float4*)(W + (size_t)k * HID + tc * 8);
            const float4 w1 = *(const float4*)(W + (size_t)k * HID + tc * 8 + 4);
            #pragma unroll
            for (int i = 0; i < 4; i++) {
                float hv = hs[tr + 16 * i][k];
                acc[i][0] = fmaf(hv, w0.x, acc[i][0]);
                acc[i][1] = fmaf(hv, w0.y, acc[i][1]);
                acc[i][2] = fmaf(hv, w0.z, acc[i][2]);
                acc[i][3] = fmaf(hv, w0.w, acc[i][3]);
                acc[i][4] = fmaf(hv, w1.x, acc[i][4]);
                acc[i][5] = fmaf(hv, w1.y, acc[i][5]);
                acc[i][6] = fmaf(hv, w1.z, acc[i][6]);
                acc[i][7] = fmaf(hv, w1.w, acc[i][7]);
            }
        }
    };

    // W1 -> keep in aacc
    mm(W1);
    #pragma unroll
    for (int i = 0; i < 4; i++)
        #pragma unroll
        for (int j = 0; j < 8; j++) aacc[i][j] = acc[i][j];

    // W2 -> B
    mm(W2);
    #pragma unroll
    for (int i = 0; i < 4; i++) {
        int gr = row0 + tr + 16 * i;
        if (gr < N_NODES) {
            float4 o0 = make_float4(acc[i][0], acc[i][1], acc[i][2], acc[i][3]);
            float4 o1 = make_float4(acc[i][4], acc[i][5], acc[i][6], acc[i][7]);
            *(float4*)(Bout + (size_t)gr * HID + tc * 8) = o0;
            *(float4*)(Bout + (size_t)gr * HID + tc * 8 + 4) = o1;
        }
    }

    // W3 -> combine
    mm(W3);
    const float4 b1a = *(const float4*)(b1 + tc * 8);
    const float4 b1b = *(const float4*)(b1 + tc * 8 + 4);
    const float4 b3a = *(const float4*)(b3 + tc * 8);
    const float4 b3b = *(const float4*)(b3 + tc * 8 + 4);
    #pragma unroll
    for (int i = 0; i < 4; i++) {
        int gr = row0 + tr + 16 * i;
        if (gr < N_NODES) {
            float dg = deg[gr];
            float4 o0, o1;
            o0.x = fmaf(dg, aacc[i][0] + b1a.x, acc[i][0] + b3a.x);
            o0.y = fmaf(dg, aacc[i][1] + b1a.y, acc[i][1] + b3a.y);
            o0.z = fmaf(dg, aacc[i][2] + b1a.z, acc[i][2] + b3a.z);
            o0.w = fmaf(dg, aacc[i][3] + b1a.w, acc[i][3] + b3a.w);
            o1.x = fmaf(dg, aacc[i][4] + b1b.x, acc[i][4] + b3b.x);
            o1.y = fmaf(dg, aacc[i][5] + b1b.y, acc[i][5] + b3b.y);
            o1.z = fmaf(dg, aacc[i][6] + b1b.z, acc[i][6] + b3b.z);
            o1.w = fmaf(dg, aacc[i][7] + b1b.w, acc[i][7] + b3b.w);
            *(float4*)(OUT + (size_t)gr * HID + tc * 8) = o0;
            *(float4*)(OUT + (size_t)gr * HID + tc * 8 + 4) = o1;
        }
    }
}

// ---------------- edge aggregation: OUT[i] -= sum_{e: dst=i} B[src(e)] ----------------
// one wave per node; lane owns 2 contiguous floats (512B coalesced row reads)

__global__ __launch_bounds__(256) void gather_kernel(const int* __restrict__ rowptr,
                                                     const int* __restrict__ col,
                                                     const float* __restrict__ Bmat,
                                                     float* __restrict__ OUT) {
    int wid = (blockIdx.x * 256 + threadIdx.x) >> 6;  // node
    int lane = threadIdx.x & 63;
    if (wid >= N_NODES) return;
    int s = rowptr[wid];
    int e = rowptr[wid + 1];
    float ax = 0.f, ay = 0.f;
    for (int t = s; t < e; t++) {
        int src = col[t];  // wave-uniform
        const float2 v = *(const float2*)(Bmat + (size_t)src * HID + lane * 2);
        ax += v.x;
        ay += v.y;
    }
    float2 o = *(float2*)(OUT + (size_t)wid * HID + lane * 2);
    o.x -= ax;
    o.y -= ay;
    *(float2*)(OUT + (size_t)wid * HID + lane * 2) = o;
}

// ---------------- pool (mean, with relu on load) + FFN head ----------------

__global__ __launch_bounds__(128) void pool_ffn_kernel(const float* __restrict__ H,
                                                       const int* __restrict__ batch,
                                                       const float* __restrict__ Wf1,
                                                       const float* __restrict__ bf1,
                                                       const float* __restrict__ Wf2,
                                                       const float* __restrict__ bf2,
                                                       float* __restrict__ out) {
    const int g = blockIdx.x;
    const int t = threadIdx.x;  // 0..127

    // lower_bound(batch, g) and lower_bound(batch, g+1) on sorted batch
    int lo = 0, hi = N_NODES;
    while (lo < hi) { int mid = (lo + hi) >> 1; if (batch[mid] < g) lo = mid + 1; else hi = mid; }
    const int s = lo;
    hi = N_NODES;
    while (lo < hi) { int mid = (lo + hi) >> 1; if (batch[mid] < g + 1) lo = mid + 1; else hi = mid; }
    const int e = lo;

    float sum = 0.f;
    for (int n = s; n < e; n++) sum += fmaxf(H[(size_t)n * HID + t], 0.f);
    const float cntf = (float)(e - s);
    const float gx = sum / fmaxf(cntf, 1.f);

    __shared__ float lds[HID];
    lds[t] = gx;
    __syncthreads();

    float hsum = bf1[t];
    #pragma unroll 8
    for (int k = 0; k < HID; k++) hsum = fmaf(lds[k], Wf1[k * HID + t], hsum);
    const float hr = fmaxf(hsum, 0.f);

    float p0 = hr * Wf2[t * 2 + 0];
    float p1 = hr * Wf2[t * 2 + 1];
    #pragma unroll
    for (int off = 32; off > 0; off >>= 1) {
        p0 += __shfl_down(p0, off, 64);
        p1 += __shfl_down(p1, off, 64);
    }
    __shared__ float red[4];
    if ((t & 63) == 0) {
        red[(t >> 6) * 2 + 0] = p0;
        red[(t >> 6) * 2 + 1] = p1;
    }
    __syncthreads();
    if (t == 0) {
        out[g * 2 + 0] = red[0] + red[2] + bf2[0];
        out[g * 2 + 1] = red[1] + red[3] + bf2[1];
    }
}

// ---------------- launch ----------------

extern "C" void kernel_launch(void* const* d_in, const int* in_sizes, int n_in,
                              void* d_out, int out_size, void* d_ws, size_t ws_size,
                              hipStream_t stream) {
    (void)in_sizes; (void)n_in; (void)out_size; (void)ws_size;

    const float* x     = (const float*)d_in[0];
    const int*   ei    = (const int*)d_in[1];
    const int*   batch = (const int*)d_in[2];
    const float* W1_0 = (const float*)d_in[3];
    const float* b1_0 = (const float*)d_in[4];
    const float* W2_0 = (const float*)d_in[5];
    const float* W3_0 = (const float*)d_in[6];
    const float* b3_0 = (const float*)d_in[7];
    const float* W1_1 = (const float*)d_in[8];
    const float* b1_1 = (const float*)d_in[9];
    const float* W2_1 = (const float*)d_in[10];
    const float* W3_1 = (const float*)d_in[11];
    const float* b3_1 = (const float*)d_in[12];
    const float* W1_2 = (const float*)d_in[13];
    const float* b1_2 = (const float*)d_in[14];
    const float* W2_2 = (const float*)d_in[15];
    const float* W3_2 = (const float*)d_in[16];
    const float* b3_2 = (const float*)d_in[17];
    const float* Wf1  = (const float*)d_in[18];
    const float* bf1  = (const float*)d_in[19];
    const float* Wf2  = (const float*)d_in[20];
    const float* bf2  = (const float*)d_in[21];
    float* out = (float*)d_out;

    char* ws = (char*)d_ws;
    size_t off = 0;
    auto alloc = [&](size_t bytes) {
        void* p = ws + off;
        off += (bytes + 255) & ~(size_t)255;
        return p;
    };
    float* F1     = (float*)alloc((size_t)N_NODES * HID * 4);
    float* F2     = (float*)alloc((size_t)N_NODES * HID * 4);
    float* Bm     = (float*)alloc((size_t)N_NODES * HID * 4);
    float* degf   = (float*)alloc((size_t)N_NODES * 4);
    int*   rowptr = (int*)alloc((size_t)(N_NODES + 1) * 4);
    int*   cursor = (int*)alloc((size_t)N_NODES * 4);
    int*   col    = (int*)alloc((size_t)N_EDGES * 4);

    // CSR build (edge_index is shared by all 3 layers)
    zero_kernel<<<(N_NODES + 255) / 256, 256, 0, stream>>>(cursor, N_NODES);
    hist_kernel<<<(N_EDGES + 255) / 256, 256, 0, stream>>>(ei, cursor);
    scan_kernel<<<1, 1024, 0, stream>>>(cursor, rowptr, degf);
    fill_kernel<<<(N_EDGES + 255) / 256, 256, 0, stream>>>(ei, cursor, col);

    const int gemm_grid = (N_NODES + 63) / 64;
    const int gather_grid = (N_NODES * 64 + 255) / 256;

    // layer 0: x(37) -> F1
    leconv_gemm<IN_DIM, false><<<gemm_grid, 256, 0, stream>>>(x, W1_0, b1_0, W2_0, W3_0, b3_0, degf, Bm, F1);
    gather_kernel<<<gather_grid, 256, 0, stream>>>(rowptr, col, Bm, F1);
    // layer 1: relu(F1) -> F2
    leconv_gemm<HID, true><<<gemm_grid, 256, 0, stream>>>(F1, W1_1, b1_1, W2_1, W3_1, b3_1, degf, Bm, F2);
    gather_kernel<<<gather_grid, 256, 0, stream>>>(rowptr, col, Bm, F2);
    // layer 2: relu(F2) -> F1
    leconv_gemm<HID, true><<<gemm_grid, 256, 0, stream>>>(F2, W1_2, b1_2, W2_2, W3_2, b3_2, degf, Bm, F1);
    gather_kernel<<<gather_grid, 256, 0, stream>>>(rowptr, col, Bm, F1);
    // pool + FFN
    pool_ffn_kernel<<<N_GRAPHS, 128, 0, stream>>>(F1, batch, Wf1, bf1, Wf2, bf2, out);
}

// Round 2
// 712.394 us; speedup vs baseline: 1.8063x; 1.8063x over previous
//
#include <hip/hip_runtime.h>
#include <hip/hip_bf16.h>
#include <cstdint>

#define N_NODES 100000
#define N_EDGES 1600000
#define N_GRAPHS 2000
#define IN_DIM 37
#define HID 128

typedef __attribute__((ext_vector_type(8))) short short8;
typedef __attribute__((ext_vector_type(4))) float f32x4;

static __device__ __forceinline__ short bf16_bits(float f) {
    __hip_bfloat16 h = __float2bfloat16(f);
    return *reinterpret_cast<short*>(&h);
}

// ---------------- CSR build ----------------

__global__ __launch_bounds__(256) void zero_kernel(int* __restrict__ p, int n) {
    int i = blockIdx.x * 256 + threadIdx.x;
    if (i < n) p[i] = 0;
}

__global__ __launch_bounds__(256) void hist_kernel(const int* __restrict__ ei, int* __restrict__ cnt) {
    int e = blockIdx.x * 256 + threadIdx.x;
    if (e < N_EDGES) atomicAdd(&cnt[ei[N_EDGES + e]], 1);
}

// per-1024-block exclusive scan; partial[i] = local excl, bsum[b] = block total
__global__ __launch_bounds__(1024) void scan_blocks(const int* __restrict__ cnt,
                                                    int* __restrict__ partial,
                                                    int* __restrict__ bsum) {
    __shared__ int ws[16];
    const int tid = threadIdx.x, lane = tid & 63, wv = tid >> 6;
    const int i = blockIdx.x * 1024 + tid;
    int v0 = (i < N_NODES) ? cnt[i] : 0;
    int v = v0;
    #pragma unroll
    for (int off = 1; off < 64; off <<= 1) {
        int n = __shfl_up(v, off, 64);
        if (lane >= off) v += n;
    }
    if (lane == 63) ws[wv] = v;
    __syncthreads();
    int woff = 0, tot = 0;
    #pragma unroll
    for (int w = 0; w < 16; w++) {
        int s = ws[w];
        if (w < wv) woff += s;
        tot += s;
    }
    if (i < N_NODES) partial[i] = woff + v - v0;
    if (tid == 0) bsum[blockIdx.x] = tot;
}

__global__ __launch_bounds__(1024) void scan_finalize(const int* __restrict__ partial,
                                                      const int* __restrict__ bsum,
                                                      const int* __restrict__ cnt,
                                                      int* __restrict__ rowptr,
                                                      int* __restrict__ cursor,
                                                      float* __restrict__ degf) {
    __shared__ int off_s;
    const int tid = threadIdx.x, b = blockIdx.x;
    if (tid < 64) {
        int acc = 0;
        for (int j = tid; j < b; j += 64) acc += bsum[j];
        #pragma unroll
        for (int off = 32; off; off >>= 1) acc += __shfl_down(acc, off, 64);
        if (tid == 0) off_s = acc;
    }
    __syncthreads();
    const int base = off_s;
    const int i = b * 1024 + tid;
    if (i < N_NODES) {
        int r = base + partial[i];
        rowptr[i] = r;
        cursor[i] = r;
        degf[i] = (float)cnt[i];
    }
    if (b == 0 && tid == 0) rowptr[N_NODES] = N_EDGES;
}

__global__ __launch_bounds__(256) void fill_kernel(const int* __restrict__ ei,
                                                   int* __restrict__ cursor,
                                                   int* __restrict__ col) {
    int e = blockIdx.x * 256 + threadIdx.x;
    if (e < N_EDGES) {
        int s = ei[e];
        int d = ei[N_EDGES + e];
        int pos = atomicAdd(&cursor[d], 1);
        col[pos] = s;
    }
}

// ---------------- weight pack + x convert ----------------
// packed[kb*4096 + t*512 + lane*8 + i] = bf16(W[kb*32 + (lane>>4)*8 + i][t*16 + (lane&15)])

struct PackArgs {
    const float* w[9];
    short* o[9];
    int K32[9];
    int Kin[9];
};

__global__ __launch_bounds__(256) void pack_w(PackArgs pa) {
    const int m = blockIdx.y;
    const int idx = blockIdx.x * 256 + threadIdx.x;
    if (idx >= pa.K32[m] * 4096) return;
    const int i = idx & 7, lane = (idx >> 3) & 63, t = (idx >> 9) & 7, kb = idx >> 12;
    const int k = kb * 32 + (lane >> 4) * 8 + i;
    const int c = t * 16 + (lane & 15);
    float v = (k < pa.Kin[m]) ? pa.w[m][k * HID + c] : 0.f;
    pa.o[m][idx] = bf16_bits(v);
}

__global__ __launch_bounds__(256) void conv_x(const float* __restrict__ x, short* __restrict__ Xb) {
    const int idx = blockIdx.x * 256 + threadIdx.x;
    if (idx >= N_NODES * 64) return;
    const int n = idx >> 6, k = idx & 63;
    float v = (k < IN_DIM) ? x[n * IN_DIM + k] : 0.f;
    Xb[idx] = bf16_bits(v);
}

// ---------------- fused LEConv GEMM (MFMA bf16, fp32 accum) ----------------
// acc1 = h@W1, acc2 = h@W2 -> Bout (bf16), acc3 = h@W3
// OUT = deg*(acc1+b1) + acc3 + b3   (fp32; gather subtracts agg later)

template <int K32>
__global__ __launch_bounds__(256) void leconv_mfma(
    const short* __restrict__ Hb,
    const short* __restrict__ Wp1, const short* __restrict__ Wp2, const short* __restrict__ Wp3,
    const float* __restrict__ b1v, const float* __restrict__ b3v,
    const float* __restrict__ deg,
    short* __restrict__ Bout, float* __restrict__ OUT) {
    constexpr int K = K32 * 32;
    const int tid = threadIdx.x;
    const int wave = tid >> 6, lane = tid & 63;
    const int row_base = blockIdx.x * 64 + wave * 16;
    const int r15 = lane & 15, kg = lane >> 4;

    int arow = row_base + r15;
    if (arow >= N_NODES) arow = N_NODES - 1;
    const short* aptr = Hb + (size_t)arow * K + kg * 8;

    f32x4 acc1[8], acc2[8], acc3[8];
    #pragma unroll
    for (int t = 0; t < 8; t++) {
        acc1[t] = (f32x4)0.f; acc2[t] = (f32x4)0.f; acc3[t] = (f32x4)0.f;
    }

    #pragma unroll
    for (int kb = 0; kb < K32; kb++) {
        short8 a = *(const short8*)(aptr + kb * 32);
        #pragma unroll
        for (int t = 0; t < 8; t++) {
            const int widx = (kb * 8 + t) * 512 + lane * 8;
            short8 w1 = *(const short8*)(Wp1 + widx);
            short8 w2 = *(const short8*)(Wp2 + widx);
            short8 w3 = *(const short8*)(Wp3 + widx);
            acc1[t] = __builtin_amdgcn_mfma_f32_16x16x32_bf16(a, w1, acc1[t], 0, 0, 0);
            acc2[t] = __builtin_amdgcn_mfma_f32_16x16x32_bf16(a, w2, acc2[t], 0, 0, 0);
            acc3[t] = __builtin_amdgcn_mfma_f32_16x16x32_bf16(a, w3, acc3[t], 0, 0, 0);
        }
    }

    // C/D layout: col = lane&15 (within tile), row = (lane>>4)*4 + reg
    float dg[4];
    int grow[4];
    bool ok[4];
    #pragma unroll
    for (int i = 0; i < 4; i++) {
        grow[i] = row_base + kg * 4 + i;
        ok[i] = grow[i] < N_NODES;
        dg[i] = ok[i] ? deg[grow[i]] : 0.f;
    }
    #pragma unroll
    for (int t = 0; t < 8; t++) {
        const int c = t * 16 + r15;
        const float bb1 = b1v[c], bb3 = b3v[c];
        #pragma unroll
        for (int i = 0; i < 4; i++) {
            if (ok[i]) {
                size_t o = (size_t)grow[i] * HID + c;
                OUT[o] = dg[i] * (acc1[t][i] + bb1) + acc3[t][i] + bb3;
                Bout[o] = bf16_bits(acc2[t][i]);
            }
        }
    }
}

// ---------------- gather: Hb[i] = bf16(relu(OUT[i] - sum_{e:dst=i} Bm[src(e)])) ----------------

__global__ __launch_bounds__(256) void gather_kernel(const int* __restrict__ rowptr,
                                                     const int* __restrict__ col,
                                                     const short* __restrict__ Bm,
                                                     const float* __restrict__ OUT,
                                                     short* __restrict__ Hb) {
    const int wid = (blockIdx.x * 256 + threadIdx.x) >> 6;
    const int lane = threadIdx.x & 63;
    if (wid >= N_NODES) return;
    const int s = rowptr[wid], e = rowptr[wid + 1];
    float ax = 0.f, ay = 0.f;
    int t = s;
    for (; t + 1 < e; t += 2) {
        int s0 = col[t], s1 = col[t + 1];
        uint32_t u0 = *(const uint32_t*)(Bm + (size_t)s0 * HID + lane * 2);
        uint32_t u1 = *(const uint32_t*)(Bm + (size_t)s1 * HID + lane * 2);
        union { uint32_t u; struct { uint16_t lo, hi; } s; } c0{u0}, c1{u1};
        ax += __bfloat162float(*(__hip_bfloat16*)&c0.s.lo) + __bfloat162float(*(__hip_bfloat16*)&c1.s.lo);
        ay += __bfloat162float(*(__hip_bfloat16*)&c0.s.hi) + __bfloat162float(*(__hip_bfloat16*)&c1.s.hi);
    }
    if (t < e) {
        int s0 = col[t];
        uint32_t u0 = *(const uint32_t*)(Bm + (size_t)s0 * HID + lane * 2);
        union { uint32_t u; struct { uint16_t lo, hi; } s; } c0{u0};
        ax += __bfloat162float(*(__hip_bfloat16*)&c0.s.lo);
        ay += __bfloat162float(*(__hip_bfloat16*)&c0.s.hi);
    }
    const float2 o = *(const float2*)(OUT + (size_t)wid * HID + lane * 2);
    uint32_t r = ((uint32_t)(uint16_t)bf16_bits(fmaxf(o.y - ay, 0.f)) << 16) |
                 (uint16_t)bf16_bits(fmaxf(o.x - ax, 0.f));
    *(uint32_t*)(Hb + (size_t)wid * HID + lane * 2) = r;
}

// ---------------- pool (mean of relu'd bf16 H) + FFN head ----------------

__global__ __launch_bounds__(128) void pool_ffn_kernel(const short* __restrict__ H,
                                                       const int* __restrict__ batch,
                                                       const float* __restrict__ Wf1,
                                                       const float* __restrict__ bf1,
                                                       const float* __restrict__ Wf2,
                                                       const float* __restrict__ bf2,
                                                       float* __restrict__ out) {
    const int g = blockIdx.x;
    const int t = threadIdx.x;  // 0..127

    int lo = 0, hi = N_NODES;
    while (lo < hi) { int mid = (lo + hi) >> 1; if (batch[mid] < g) lo = mid + 1; else hi = mid; }
    const int s = lo;
    hi = N_NODES;
    while (lo < hi) { int mid = (lo + hi) >> 1; if (batch[mid] < g + 1) lo = mid + 1; else hi = mid; }
    const int e = lo;

    float sum = 0.f;
    for (int n = s; n < e; n++) {
        short b = H[(size_t)n * HID + t];
        sum += __bfloat162float(*(__hip_bfloat16*)&b);
    }
    const float cntf = (float)(e - s);
    const float gx = sum / fmaxf(cntf, 1.f);

    __shared__ float lds[HID];
    lds[t] = gx;
    __syncthreads();

    float hsum = bf1[t];
    #pragma unroll 8
    for (int k = 0; k < HID; k++) hsum = fmaf(lds[k], Wf1[k * HID + t], hsum);
    const float hr = fmaxf(hsum, 0.f);

    float p0 = hr * Wf2[t * 2 + 0];
    float p1 = hr * Wf2[t * 2 + 1];
    #pragma unroll
    for (int off = 32; off > 0; off >>= 1) {
        p0 += __shfl_down(p0, off, 64);
        p1 += __shfl_down(p1, off, 64);
    }
    __shared__ float red[4];
    if ((t & 63) == 0) {
        red[(t >> 6) * 2 + 0] = p0;
        red[(t >> 6) * 2 + 1] = p1;
    }
    __syncthreads();
    if (t == 0) {
        out[g * 2 + 0] = red[0] + red[2] + bf2[0];
        out[g * 2 + 1] = red[1] + red[3] + bf2[1];
    }
}

// ---------------- launch ----------------

extern "C" void kernel_launch(void* const* d_in, const int* in_sizes, int n_in,
                              void* d_out, int out_size, void* d_ws, size_t ws_size,
                              hipStream_t stream) {
    (void)in_sizes; (void)n_in; (void)out_size; (void)ws_size;

    const float* x     = (const float*)d_in[0];
    const int*   ei    = (const int*)d_in[1];
    const int*   batch = (const int*)d_in[2];
    const float* W[9] = {
        (const float*)d_in[3],  (const float*)d_in[5],  (const float*)d_in[6],   // W1_0 W2_0 W3_0
        (const float*)d_in[8],  (const float*)d_in[10], (const float*)d_in[11],  // W1_1 W2_1 W3_1
        (const float*)d_in[13], (const float*)d_in[15], (const float*)d_in[16]}; // W1_2 W2_2 W3_2
    const float* b1_0 = (const float*)d_in[4];
    const float* b3_0 = (const float*)d_in[7];
    const float* b1_1 = (const float*)d_in[9];
    const float* b3_1 = (const float*)d_in[12];
    const float* b1_2 = (const float*)d_in[14];
    const float* b3_2 = (const float*)d_in[17];
    const float* Wf1  = (const float*)d_in[18];
    const float* bf1  = (const float*)d_in[19];
    const float* Wf2  = (const float*)d_in[20];
    const float* bf2  = (const float*)d_in[21];
    float* out = (float*)d_out;

    char* ws = (char*)d_ws;
    size_t off = 0;
    auto alloc = [&](size_t bytes) {
        void* p = ws + off;
        off += (bytes + 255) & ~(size_t)255;
        return p;
    };
    float* OUT    = (float*)alloc((size_t)N_NODES * HID * 4);
    short* Bm     = (short*)alloc((size_t)N_NODES * HID * 2);
    short* Hb     = (short*)alloc((size_t)N_NODES * HID * 2);
    short* Xb     = (short*)alloc((size_t)N_NODES * 64 * 2);
    float* degf   = (float*)alloc((size_t)N_NODES * 4);
    int*   rowptr = (int*)alloc((size_t)(N_NODES + 1) * 4);
    int*   cursor = (int*)alloc((size_t)N_NODES * 4);
    int*   col    = (int*)alloc((size_t)N_EDGES * 4);
    int*   partial= (int*)alloc((size_t)N_NODES * 4);
    int*   bsum   = (int*)alloc(1024);
    short* P[9];
    for (int m = 0; m < 9; m++) P[m] = (short*)alloc(16384 * 2);

    // CSR build
    const int NSB = (N_NODES + 1023) / 1024;  // 98
    zero_kernel<<<(N_NODES + 255) / 256, 256, 0, stream>>>(cursor, N_NODES);
    hist_kernel<<<(N_EDGES + 255) / 256, 256, 0, stream>>>(ei, cursor);
    scan_blocks<<<NSB, 1024, 0, stream>>>(cursor, partial, bsum);
    scan_finalize<<<NSB, 1024, 0, stream>>>(partial, bsum, cursor, rowptr, cursor, degf);
    fill_kernel<<<(N_EDGES + 255) / 256, 256, 0, stream>>>(ei, cursor, col);

    // weight pack + x convert
    PackArgs pa;
    for (int m = 0; m < 9; m++) {
        pa.w[m] = W[m];
        pa.o[m] = P[m];
        pa.K32[m] = (m < 3) ? 2 : 4;
        pa.Kin[m] = (m < 3) ? IN_DIM : HID;
    }
    pack_w<<<dim3(64, 9), 256, 0, stream>>>(pa);
    conv_x<<<(N_NODES * 64 + 255) / 256, 256, 0, stream>>>(x, Xb);

    const int gemm_grid = (N_NODES + 63) / 64;
    const int gather_grid = (N_NODES * 64 + 255) / 256;

    // layer 0
    leconv_mfma<2><<<gemm_grid, 256, 0, stream>>>(Xb, P[0], P[1], P[2], b1_0, b3_0, degf, Bm, OUT);
    gather_kernel<<<gather_grid, 256, 0, stream>>>(rowptr, col, Bm, OUT, Hb);
    // layer 1
    leconv_mfma<4><<<gemm_grid, 256, 0, stream>>>(Hb, P[3], P[4], P[5], b1_1, b3_1, degf, Bm, OUT);
    gather_kernel<<<gather_grid, 256, 0, stream>>>(rowptr, col, Bm, OUT, Hb);
    // layer 2
    leconv_mfma<4><<<gemm_grid, 256, 0, stream>>>(Hb, P[6], P[7], P[8], b1_2, b3_2, degf, Bm, OUT);
    gather_kernel<<<gather_grid, 256, 0, stream>>>(rowptr, col, Bm, OUT, Hb);
    // pool + FFN
    pool_ffn_kernel<<<N_GRAPHS, 128, 0, stream>>>(Hb, batch, Wf1, bf1, Wf2, bf2, out);
}